// Round 3
// baseline (211.286 us; speedup 1.0000x reference)
//
#include <hip/hip_runtime.h>

typedef __attribute__((ext_vector_type(8))) short short8;
typedef __attribute__((ext_vector_type(4))) float f32x4;

#define D_KV   64
#define SEQ    4096
#define NBATCH 4
#define DMODEL 1024

static __device__ __forceinline__ unsigned short f32_to_bf16(float f) {
  unsigned u = __builtin_bit_cast(unsigned, f);
  u = (u + 0x7FFFu + ((u >> 16) & 1u)) >> 16;  // round-nearest-even
  return (unsigned short)u;
}

// ---------------- kernel 1: weights f32 -> bf16 (once per launch) ------------
__global__ __launch_bounds__(256) void wcvt_kernel(
    const float* __restrict__ wq, const float* __restrict__ wk,
    const float* __restrict__ wv, unsigned short* __restrict__ wbf) {
  int i = blockIdx.x * 256 + threadIdx.x;  // 0 .. 65535 (64*1024)
  wbf[i]          = f32_to_bf16(wq[i]);
  wbf[i + 65536]  = f32_to_bf16(wk[i]);
  wbf[i + 131072] = f32_to_bf16(wv[i]);
}

// ---------------- kernel 2: QKV projection, in-block split-K ----------------
// 1024 blocks x 16 rows; wave w handles K in [w*256, w*256+256); LDS atomicAdd
// combine; bias+bf16-cvt+store in a final pass.
// Q scaled by 1/sqrt(64); K row-major; V stored transposed [B][64][SEQ].
__global__ __launch_bounds__(256) void qkv_proj_kernel(
    const float* __restrict__ x, const unsigned short* __restrict__ wbf,
    const float* __restrict__ bq, const float* __restrict__ bk,
    const float* __restrict__ bv,
    unsigned short* __restrict__ Q, unsigned short* __restrict__ Kt,
    unsigned short* __restrict__ VT) {
  __shared__ float lds_acc[16][200];  // [row][qkv-col 0..191], padded
  const int tid = threadIdx.x;
  const int lane = tid & 63;
  const int wave = tid >> 6;
  const int l16 = lane & 15, lq = lane >> 4;
  const long rowbase = (long)blockIdx.x * 16;

  for (int i = tid; i < 16 * 200; i += 256) (&lds_acc[0][0])[i] = 0.f;
  __syncthreads();

  const float* xrow = x + (rowbase + l16) * DMODEL + wave * 256;

  f32x4 acc[12];
#pragma unroll
  for (int i = 0; i < 12; ++i) acc[i] = (f32x4){0.f, 0.f, 0.f, 0.f};

  for (int kc = 0; kc < 8; ++kc) {
    const int k0 = kc * 32 + lq * 8;
    short8 a;
    {
      f32x4 f0 = *reinterpret_cast<const f32x4*>(xrow + k0);
      f32x4 f1 = *reinterpret_cast<const f32x4*>(xrow + k0 + 4);
#pragma unroll
      for (int j = 0; j < 4; ++j) {
        a[j]     = (short)f32_to_bf16(f0[j]);
        a[4 + j] = (short)f32_to_bf16(f1[j]);
      }
    }
#pragma unroll
    for (int nt = 0; nt < 12; ++nt) {
      const unsigned short* wrow =
          wbf + (long)((nt >> 2) * 64 + (nt & 3) * 16 + l16) * DMODEL + wave * 256 + k0;
      short8 b = *reinterpret_cast<const short8*>(wrow);
      acc[nt] = __builtin_amdgcn_mfma_f32_16x16x32_bf16(a, b, acc[nt], 0, 0, 0);
    }
  }

#pragma unroll
  for (int nt = 0; nt < 12; ++nt)
#pragma unroll
    for (int r = 0; r < 4; ++r)
      atomicAdd(&lds_acc[lq * 4 + r][(nt >> 2) * 64 + (nt & 3) * 16 + l16],
                acc[nt][r]);
  __syncthreads();

  const int row = tid >> 4, c16 = tid & 15;
  const long t = rowbase + row;
#pragma unroll
  for (int j = 0; j < 12; ++j) {
    const int col = c16 + 16 * j;
    const int d = col & 63;
    const float sum = lds_acc[row][col];
    if (j < 4) {
      Q[t * D_KV + d] = f32_to_bf16((sum + bq[d]) * 0.125f);  // fold 1/sqrt(64)
    } else if (j < 8) {
      Kt[t * D_KV + d] = f32_to_bf16(sum + bk[d]);
    } else {
      VT[((t >> 12) * D_KV + d) * SEQ + (t & 4095)] = f32_to_bf16(sum + bv[d]);
    }
  }
}

// ---------------- kernel 3: causal flash attention, swapped-operand ---------
// One 16-row Q tile per block; 4 waves split KV round-robin; swapped MFMA
// operands make softmax lane-local (2 shuffles/iter instead of 32).
__global__ __launch_bounds__(256) void attn_kernel(
    const unsigned short* __restrict__ Q, const unsigned short* __restrict__ Kt,
    const unsigned short* __restrict__ VT, float* __restrict__ out) {
  __shared__ __align__(16) unsigned short p_lds[4][16][72];  // [wave][q][k]
  __shared__ __align__(16) float lds_o[4][16][68];           // [wave][q][d]
  __shared__ float lds_ml[4][16][2];
  __shared__ float lds_gl[16];

  const int tid = threadIdx.x;
  const int lane = tid & 63;
  const int wave = tid >> 6;
  const int l16 = lane & 15, lq = lane >> 4;
  const int b = blockIdx.y;
  const int tile = 255 - blockIdx.x;  // heavy tiles dispatch first
  const int qbase = tile * 16;
  const long qrow = (long)b * SEQ + qbase;

  short8 qf[2];  // B-frag of Q: col=l16 -> Q row qbase+l16
#pragma unroll
  for (int c = 0; c < 2; ++c)
    qf[c] = *reinterpret_cast<const short8*>(Q + (qrow + l16) * D_KV + c * 32 + lq * 8);

  f32x4 o[4];  // O^T: o[dt][r] = O[q=l16][d=dt*16+lq*4+r]
#pragma unroll
  for (int dt = 0; dt < 4; ++dt) o[dt] = (f32x4){0.f, 0.f, 0.f, 0.f};
  float m = -INFINITY, ell = 0.f;  // per-lane state for q = qbase + l16

  const int nkv = qbase / 64 + 1;  // KV tiles of 64 cols
  for (int kt = wave; kt < nkv; kt += 4) {
    const int kvbase = kt * 64;
    f32x4 s[4];  // S^T: s[ct][r] = S[q=l16][k=kvbase+ct*16+lq*4+r]
#pragma unroll
    for (int ct = 0; ct < 4; ++ct) s[ct] = (f32x4){0.f, 0.f, 0.f, 0.f};
#pragma unroll
    for (int ct = 0; ct < 4; ++ct) {
      const unsigned short* krow = Kt + ((long)b * SEQ + kvbase + ct * 16 + l16) * D_KV;
#pragma unroll
      for (int c = 0; c < 2; ++c) {
        short8 kf = *reinterpret_cast<const short8*>(krow + c * 32 + lq * 8);
        s[ct] = __builtin_amdgcn_mfma_f32_16x16x32_bf16(kf, qf[c], s[ct], 0, 0, 0);
      }
    }
    if (kt == nkv - 1) {  // only the diagonal tile needs masking
      const int qg = qbase + l16;
#pragma unroll
      for (int ct = 0; ct < 4; ++ct)
#pragma unroll
        for (int r = 0; r < 4; ++r)
          if (kvbase + ct * 16 + lq * 4 + r > qg) s[ct][r] = -INFINITY;
    }
    // lane-local softmax over the 16 held k values, then 4-lane-group reduce
    float mx = -INFINITY;
#pragma unroll
    for (int ct = 0; ct < 4; ++ct)
#pragma unroll
      for (int r = 0; r < 4; ++r) mx = fmaxf(mx, s[ct][r]);
    mx = fmaxf(mx, __shfl_xor(mx, 16, 64));
    mx = fmaxf(mx, __shfl_xor(mx, 32, 64));
    const float nm = fmaxf(m, mx);
    const float alpha = __expf(m - nm);  // exp(-inf)=0 on first tile
    float rs = 0.f;
#pragma unroll
    for (int ct = 0; ct < 4; ++ct)
#pragma unroll
      for (int r = 0; r < 4; ++r) {
        const float p = __expf(s[ct][r] - nm);
        s[ct][r] = p;
        rs += p;
      }
    rs += __shfl_xor(rs, 16, 64);
    rs += __shfl_xor(rs, 32, 64);
    ell = ell * alpha + rs;
    m = nm;
#pragma unroll
    for (int dt = 0; dt < 4; ++dt) o[dt] *= alpha;
    // P^T (regs) -> p_lds[q][k] -> B-frag for PV. Per-wave buffer; same-wave
    // DS ops are ordered by the compiler's lgkmcnt -> no barrier needed.
#pragma unroll
    for (int ct = 0; ct < 4; ++ct)
#pragma unroll
      for (int r = 0; r < 4; ++r)
        p_lds[wave][l16][ct * 16 + lq * 4 + r] = f32_to_bf16(s[ct][r]);
    short8 pf[2];
#pragma unroll
    for (int c = 0; c < 2; ++c)
      pf[c] = *reinterpret_cast<const short8*>(&p_lds[wave][l16][c * 32 + lq * 8]);
#pragma unroll
    for (int dt = 0; dt < 4; ++dt) {
      const unsigned short* vrow = VT + ((long)b * D_KV + dt * 16 + l16) * SEQ + kvbase;
#pragma unroll
      for (int c = 0; c < 2; ++c) {
        short8 vf = *reinterpret_cast<const short8*>(vrow + c * 32 + lq * 8);
        o[dt] = __builtin_amdgcn_mfma_f32_16x16x32_bf16(vf, pf[c], o[dt], 0, 0, 0);
      }
    }
  }

  // ---- cross-wave combine: out = sum_w o_w*exp(m_w-g) / sum_w l_w*exp(m_w-g)
  if (lane < 16) {
    lds_ml[wave][l16][0] = m;
    lds_ml[wave][l16][1] = ell;
  }
  __syncthreads();
  const float m0 = lds_ml[0][l16][0], m1 = lds_ml[1][l16][0];
  const float m2 = lds_ml[2][l16][0], m3 = lds_ml[3][l16][0];
  const float g = fmaxf(fmaxf(m0, m1), fmaxf(m2, m3));
  const float gl = lds_ml[0][l16][1] * __expf(m0 - g) +
                   lds_ml[1][l16][1] * __expf(m1 - g) +
                   lds_ml[2][l16][1] * __expf(m2 - g) +
                   lds_ml[3][l16][1] * __expf(m3 - g);
  const float myscale = __expf(m - g);
  if (wave == 0 && lane < 16) lds_gl[l16] = gl;
#pragma unroll
  for (int dt = 0; dt < 4; ++dt)
#pragma unroll
    for (int r = 0; r < 4; ++r)
      lds_o[wave][l16][dt * 16 + lq * 4 + r] = o[dt][r] * myscale;
  __syncthreads();
#pragma unroll
  for (int j = 0; j < 4; ++j) {
    const int e = tid + 256 * j;
    const int row = e >> 6, col = e & 63;
    const float sum = lds_o[0][row][col] + lds_o[1][row][col] +
                      lds_o[2][row][col] + lds_o[3][row][col];
    out[(qrow + row) * D_KV + col] = sum / lds_gl[row];
  }
}

// ---------------- launch ----------------------------------------------------
extern "C" void kernel_launch(void* const* d_in, const int* in_sizes, int n_in,
                              void* d_out, int out_size, void* d_ws, size_t ws_size,
                              hipStream_t stream) {
  const float* x  = (const float*)d_in[0];
  const float* wq = (const float*)d_in[1];
  const float* bq = (const float*)d_in[2];
  const float* wk = (const float*)d_in[3];
  const float* bk = (const float*)d_in[4];
  const float* wv = (const float*)d_in[5];
  const float* bv = (const float*)d_in[6];
  float* out = (float*)d_out;

  unsigned short* ws  = (unsigned short*)d_ws;
  unsigned short* wbf = ws;             // 3*64*1024        = 196608 shorts
  unsigned short* Q   = ws + 196608;    // 16384*64         = 1048576
  unsigned short* Kt  = Q + 1048576;
  unsigned short* VT  = Kt + 1048576;   // [B][64][SEQ]

  wcvt_kernel<<<256, 256, 0, stream>>>(wq, wk, wv, wbf);
  qkv_proj_kernel<<<1024, 256, 0, stream>>>(x, wbf, bq, bk, bv, Q, Kt, VT);
  dim3 ag(256, NBATCH);
  attn_kernel<<<ag, 256, 0, stream>>>(Q, Kt, VT, out);
}

// Round 4
// 62.586 us; speedup vs baseline: 3.3759x; 3.3759x over previous
//
#include <hip/hip_runtime.h>

typedef __attribute__((ext_vector_type(8))) short short8;
typedef __attribute__((ext_vector_type(4))) short short4v;
typedef __attribute__((ext_vector_type(4))) float f32x4;

#define D_KV   64
#define SEQ    4096
#define NBATCH 4
#define DMODEL 1024

static __device__ __forceinline__ unsigned short f32_to_bf16(float f) {
  unsigned u = __builtin_bit_cast(unsigned, f);
  u = (u + 0x7FFFu + ((u >> 16) & 1u)) >> 16;  // round-nearest-even
  return (unsigned short)u;
}

// ---------------- kernel 1: weights f32 -> bf16, MFMA-fragment order --------
// wfrag[((nt*32 + ks)*64 + lane)*8 + j] = W_mat[(nt&3)*16 + (lane&15)]
//                                             [ks*32 + (lane>>4)*8 + j]
// nt: 0-3 Q, 4-7 K, 8-11 V.  Makes proj's B-loads lane-consecutive (coalesced).
__global__ __launch_bounds__(256) void wcvt_kernel(
    const float* __restrict__ wq, const float* __restrict__ wk,
    const float* __restrict__ wv, unsigned short* __restrict__ wfrag) {
  const int fid = blockIdx.x * 256 + threadIdx.x;  // 0..24575
  const int nt = fid >> 11, ks = (fid >> 6) & 31, lane = fid & 63;
  const int l16 = lane & 15, lq = lane >> 4;
  const float* w = (nt < 4) ? wq : (nt < 8) ? wk : wv;
  const float* src = w + ((nt & 3) * 16 + l16) * DMODEL + ks * 32 + lq * 8;
  short8 v;
#pragma unroll
  for (int j = 0; j < 8; ++j) v[j] = (short)f32_to_bf16(src[j]);
  *reinterpret_cast<short8*>(wfrag + (long)fid * 8) = v;
}

// ---------------- kernel 2: QKV projection ----------------------------------
// 1024 blocks x 16 rows. x staged coalesced into XOR-swizzled LDS; weights
// read coalesced from wfrag (L2-resident); outputs stored in fragment order:
//  Qf[((t>>4)*2+c)*512 + lane'*8 + j]                   = Q[t][c*32+lq'*8+j]
//  Kf[(((t>>6)*4+(t>>4&3))*2+c)*512 + lane'*8 + j]      = K[t][c*32+lq'*8+j]
//  Vf[(((t>>6)*4+dt)*2+(t>>5&1))*512 + lane'*8 + (t&7)] = V[t][dt*16+l16']
__global__ __launch_bounds__(256) void qkv_proj_kernel(
    const float* __restrict__ x, const unsigned short* __restrict__ wfrag,
    const float* __restrict__ bq, const float* __restrict__ bk,
    const float* __restrict__ bv,
    unsigned short* __restrict__ Qf, unsigned short* __restrict__ Kf,
    unsigned short* __restrict__ Vf) {
  __shared__ __align__(16) unsigned short lds_x[16 * 64];  // 2KB, XOR-swizzled
  const int tid = threadIdx.x, lane = tid & 63, wave = tid >> 6;
  const int l16 = lane & 15, lq = lane >> 4;
  const long rowbase = (long)blockIdx.x * 16;

  // staging map: thread -> (row, 4-float quad); coalesced 256B runs per row
  const int srow = tid >> 4, sq = tid & 15;
  const float* sgptr = x + (rowbase + srow) * DMODEL + sq * 4;
  const int swz_w = srow * 128 + ((sq * 8) ^ ((srow & 7) << 4));
  unsigned char* lx = (unsigned char*)lds_x;

  f32x4 acc[3];
#pragma unroll
  for (int i = 0; i < 3; ++i) acc[i] = (f32x4){0.f, 0.f, 0.f, 0.f};

  const unsigned short* wbase = wfrag + (long)(3 * wave) * 16384 + lane * 8;

  for (int s = 0; s < 16; ++s) {
    // issue global loads first (overlap with prior step's MFMAs)
    const f32x4 xv = *reinterpret_cast<const f32x4*>(sgptr + s * 64);
    short8 wv[3][2];
#pragma unroll
    for (int i = 0; i < 3; ++i)
#pragma unroll
      for (int kc = 0; kc < 2; ++kc)
        wv[i][kc] = *reinterpret_cast<const short8*>(
            wbase + (long)i * 16384 + (2 * s + kc) * 512);
    __syncthreads();  // prior step's ds_reads complete
    short4v xs;
#pragma unroll
    for (int j = 0; j < 4; ++j) xs[j] = (short)f32_to_bf16(xv[j]);
    *reinterpret_cast<short4v*>(lx + swz_w) = xs;
    __syncthreads();  // tile staged
    short8 a[2];
#pragma unroll
    for (int kc = 0; kc < 2; ++kc)
      a[kc] = *reinterpret_cast<const short8*>(
          lx + l16 * 128 + (((kc * 4 + lq) ^ (l16 & 7)) << 4));
#pragma unroll
    for (int i = 0; i < 3; ++i)
#pragma unroll
      for (int kc = 0; kc < 2; ++kc)
        acc[i] = __builtin_amdgcn_mfma_f32_16x16x32_bf16(a[kc], wv[i][kc],
                                                         acc[i], 0, 0, 0);
  }

#pragma unroll
  for (int i = 0; i < 3; ++i) {
    const int nt = 3 * wave + i;
    const int mat = nt >> 2;
    const int dcol = ((nt & 3) << 4) | l16;
    const float bias = (mat == 0 ? bq : mat == 1 ? bk : bv)[dcol];
    const int c = dcol >> 5, lqp = (dcol >> 3) & 3, jj = dcol & 7;
#pragma unroll
    for (int r = 0; r < 4; ++r) {
      const long t = rowbase + lq * 4 + r;
      const float sum = acc[i][r] + bias;
      if (mat == 0) {
        Qf[(((t >> 4) * 2 + c) * 64 + lqp * 16 + (t & 15)) * 8 + jj] =
            f32_to_bf16(sum * 0.125f);  // fold 1/sqrt(64)
      } else if (mat == 1) {
        Kf[((((t >> 6) * 4 + ((t >> 4) & 3)) * 2 + c) * 64 + lqp * 16 +
            (t & 15)) * 8 + jj] = f32_to_bf16(sum);
      } else {
        Vf[((((t >> 6) * 4 + (dcol >> 4)) * 2 + ((t >> 5) & 1)) * 64 +
            ((t >> 3) & 3) * 16 + (dcol & 15)) * 8 + (t & 7)] =
            f32_to_bf16(sum);
      }
    }
  }
}

// ---------------- kernel 3: causal flash attention, swapped-operand ---------
// Structure unchanged from R3 (proven): 4 waves split KV round-robin,
// lane-local softmax via swapped MFMA operands. Only the fragment loads
// changed: Qf/Kf/Vf are pre-laid-out so every load is base + lane*16B.
__global__ __launch_bounds__(256) void attn_kernel(
    const unsigned short* __restrict__ Qf, const unsigned short* __restrict__ Kf,
    const unsigned short* __restrict__ Vf, float* __restrict__ out) {
  __shared__ __align__(16) unsigned short p_lds[4][16][72];  // [wave][q][k]
  __shared__ __align__(16) float lds_o[4][16][68];           // [wave][q][d]
  __shared__ float lds_ml[4][16][2];
  __shared__ float lds_gl[16];

  const int tid = threadIdx.x;
  const int lane = tid & 63;
  const int wave = tid >> 6;
  const int l16 = lane & 15, lq = lane >> 4;
  const int b = blockIdx.y;
  const int tile = 255 - blockIdx.x;  // heavy tiles dispatch first
  const int qbase = tile * 16;
  const long qrow = (long)b * SEQ + qbase;

  short8 qf[2];
#pragma unroll
  for (int c = 0; c < 2; ++c)
    qf[c] = *reinterpret_cast<const short8*>(
        Qf + ((qrow >> 4) * 2 + c) * 512 + lane * 8);

  f32x4 o[4];  // O^T: o[dt][r] = O[q=l16][d=dt*16+lq*4+r]
#pragma unroll
  for (int dt = 0; dt < 4; ++dt) o[dt] = (f32x4){0.f, 0.f, 0.f, 0.f};
  float m = -INFINITY, ell = 0.f;  // per-lane state for q = qbase + l16

  const long ktile0 = (long)b * 64;
  const int nkv = qbase / 64 + 1;  // KV tiles of 64 cols
  for (int kt = wave; kt < nkv; kt += 4) {
    const int kvbase = kt * 64;
    const unsigned short* kb = Kf + (ktile0 + kt) * 4096 + lane * 8;
    const unsigned short* vb = Vf + (ktile0 + kt) * 4096 + lane * 8;
    f32x4 s[4];  // S^T: s[ct][r] = S[q=l16][k=kvbase+ct*16+lq*4+r]
#pragma unroll
    for (int ct = 0; ct < 4; ++ct) s[ct] = (f32x4){0.f, 0.f, 0.f, 0.f};
#pragma unroll
    for (int ct = 0; ct < 4; ++ct)
#pragma unroll
      for (int c = 0; c < 2; ++c) {
        short8 kf = *reinterpret_cast<const short8*>(kb + (ct * 2 + c) * 512);
        s[ct] = __builtin_amdgcn_mfma_f32_16x16x32_bf16(kf, qf[c], s[ct], 0, 0, 0);
      }
    if (kt == nkv - 1) {  // only the diagonal tile needs masking
      const int qg = qbase + l16;
#pragma unroll
      for (int ct = 0; ct < 4; ++ct)
#pragma unroll
        for (int r = 0; r < 4; ++r)
          if (kvbase + ct * 16 + lq * 4 + r > qg) s[ct][r] = -INFINITY;
    }
    // lane-local softmax over 16 held k values + 4-lane-group reduce
    float mx = -INFINITY;
#pragma unroll
    for (int ct = 0; ct < 4; ++ct)
#pragma unroll
      for (int r = 0; r < 4; ++r) mx = fmaxf(mx, s[ct][r]);
    mx = fmaxf(mx, __shfl_xor(mx, 16, 64));
    mx = fmaxf(mx, __shfl_xor(mx, 32, 64));
    const float nm = fmaxf(m, mx);
    const float alpha = __expf(m - nm);  // exp(-inf)=0 on first tile
    float rs = 0.f;
#pragma unroll
    for (int ct = 0; ct < 4; ++ct)
#pragma unroll
      for (int r = 0; r < 4; ++r) {
        const float p = __expf(s[ct][r] - nm);
        s[ct][r] = p;
        rs += p;
      }
    rs += __shfl_xor(rs, 16, 64);
    rs += __shfl_xor(rs, 32, 64);
    ell = ell * alpha + rs;
    m = nm;
#pragma unroll
    for (int dt = 0; dt < 4; ++dt) o[dt] *= alpha;
    // P^T (regs) -> p_lds[q][k] -> B-frag for PV. Per-wave buffer, no barrier.
#pragma unroll
    for (int ct = 0; ct < 4; ++ct)
#pragma unroll
      for (int r = 0; r < 4; ++r)
        p_lds[wave][l16][ct * 16 + lq * 4 + r] = f32_to_bf16(s[ct][r]);
    short8 pf[2];
#pragma unroll
    for (int c = 0; c < 2; ++c)
      pf[c] = *reinterpret_cast<const short8*>(&p_lds[wave][l16][c * 32 + lq * 8]);
#pragma unroll
    for (int dt = 0; dt < 4; ++dt)
#pragma unroll
      for (int c = 0; c < 2; ++c) {
        short8 vf = *reinterpret_cast<const short8*>(vb + (dt * 2 + c) * 512);
        o[dt] = __builtin_amdgcn_mfma_f32_16x16x32_bf16(vf, pf[c], o[dt], 0, 0, 0);
      }
  }

  // ---- cross-wave combine ----
  if (lane < 16) {
    lds_ml[wave][l16][0] = m;
    lds_ml[wave][l16][1] = ell;
  }
  __syncthreads();
  const float m0 = lds_ml[0][l16][0], m1 = lds_ml[1][l16][0];
  const float m2 = lds_ml[2][l16][0], m3 = lds_ml[3][l16][0];
  const float g = fmaxf(fmaxf(m0, m1), fmaxf(m2, m3));
  const float gl = lds_ml[0][l16][1] * __expf(m0 - g) +
                   lds_ml[1][l16][1] * __expf(m1 - g) +
                   lds_ml[2][l16][1] * __expf(m2 - g) +
                   lds_ml[3][l16][1] * __expf(m3 - g);
  const float myscale = __expf(m - g);
  if (wave == 0 && lane < 16) lds_gl[l16] = gl;
#pragma unroll
  for (int dt = 0; dt < 4; ++dt)
#pragma unroll
    for (int r = 0; r < 4; ++r)
      lds_o[wave][l16][dt * 16 + lq * 4 + r] = o[dt][r] * myscale;
  __syncthreads();
#pragma unroll
  for (int j = 0; j < 4; ++j) {
    const int e = tid + 256 * j;
    const int row = e >> 6, col = e & 63;
    const float sum = lds_o[0][row][col] + lds_o[1][row][col] +
                      lds_o[2][row][col] + lds_o[3][row][col];
    out[(qrow + row) * D_KV + col] = sum / lds_gl[row];
  }
}

// ---------------- launch ----------------------------------------------------
extern "C" void kernel_launch(void* const* d_in, const int* in_sizes, int n_in,
                              void* d_out, int out_size, void* d_ws, size_t ws_size,
                              hipStream_t stream) {
  const float* x  = (const float*)d_in[0];
  const float* wq = (const float*)d_in[1];
  const float* bq = (const float*)d_in[2];
  const float* wk = (const float*)d_in[3];
  const float* bk = (const float*)d_in[4];
  const float* wv = (const float*)d_in[5];
  const float* bv = (const float*)d_in[6];
  float* out = (float*)d_out;

  unsigned short* ws    = (unsigned short*)d_ws;
  unsigned short* wfrag = ws;              // 12*32*64*8 = 196608 shorts (384KB)
  unsigned short* Qf    = ws + 196608;     // 1024 tiles * 1024 = 1048576
  unsigned short* Kf    = Qf + 1048576;    // 256 kv-tiles * 4096
  unsigned short* Vf    = Kf + 1048576;

  wcvt_kernel<<<96, 256, 0, stream>>>(wq, wk, wv, wfrag);
  qkv_proj_kernel<<<1024, 256, 0, stream>>>(x, wfrag, bq, bk, bv, Qf, Kf, Vf);
  dim3 ag(256, NBATCH);
  attn_kernel<<<ag, 256, 0, stream>>>(Qf, Kf, Vf, out);
}